// Round 3
// baseline (20825.436 us; speedup 1.0000x reference)
//
#include <hip/hip_runtime.h>

// Persistent barrier-free 3-layer tanh RNN, B=32, S=1024, I=128, H=512.
// 48 blocks = 3 layers x 16 jg (32 cols). Waves within a block: (jt, bt) ->
// each wave owns a 16-batch x 16-col output tile with FULL K (no cross-wave
// reduction, no __syncthreads in the step loop). Weights live in VGPRs as
// f16 hi/lo B-frags (split-2 precision: C + (A_hi*B_lo + A_lo*B_hi)/4096).
// Sync: per-producer-wave monotonic flag counters, release/acquire at agent
// scope; consumer polls 64 flags in parallel (one per lane) via __all.
// Activations stored as SEPARATE hi/lo f16 planes -> A-frags are direct
// dwordx4 loads (zero unpack VALU).

typedef _Float16 half8 __attribute__((ext_vector_type(8)));
typedef float f32x4 __attribute__((ext_vector_type(4)));
typedef unsigned int uint32;
typedef unsigned short u16;

#define SCOPE_AGENT __HIP_MEMORY_SCOPE_AGENT
#define PLANE_HALF_ELEMS (1024 * 32 * 512)  // ushorts per plane (32 MiB); 4 planes = 128 MiB ws

__device__ __forceinline__ void split8f(const float* v, half8& hi, half8& lo) {
  union { _Float16 e[8]; half8 h; } H, L;
#pragma unroll
  for (int i = 0; i < 8; ++i) {
    _Float16 h = (_Float16)v[i];
    H.e[i] = h;
    L.e[i] = (_Float16)((v[i] - (float)h) * 4096.0f);  // exact residual scaled into f16 normal range
  }
  hi = H.h; lo = L.h;
}

__device__ __forceinline__ void frag_from_f32(const float* p, half8& hi, half8& lo) {
  float v[8];
  *(float4*)(v)     = *(const float4*)(p);
  *(float4*)(v + 4) = *(const float4*)(p + 4);
  split8f(v, hi, lo);
}

__device__ __forceinline__ float fast_tanh(float x) {
  x = fminf(20.0f, fmaxf(-20.0f, x));                      // avoid inf/inf
  float t = __builtin_amdgcn_exp2f(x * 2.885390081777927f); // e^{2x}
  return (t - 1.0f) * __builtin_amdgcn_rcpf(t + 1.0f);
}

template <int L>
__device__ void run_layer(const float* __restrict__ x, const float* __restrict__ h0,
                          const float* __restrict__ w_ih0, const float* __restrict__ w_ihs,
                          const float* __restrict__ w_hhs, const float* __restrict__ b_ihs,
                          const float* __restrict__ b_hhs,
                          u16* __restrict__ p0hi, u16* __restrict__ p0lo,
                          u16* __restrict__ p1hi, u16* __restrict__ p1lo,
                          float* __restrict__ outp, int jg) {
  constexpr int KT_IN  = (L == 0) ? 4 : 16;   // input-projection K-tiles of 32
  constexpr int KT_ALL = (L == 0) ? 20 : 32;  // + 16 recurrent K-tiles

  uint32* flags  = (uint32*)outp;                       // [3][2][32] monotonic counters, dwords [0,192)
  u16* ring_hi   = (u16*)((char*)outp + 768);           // L2 rec state, 2-slot ring [2][32][512]
  u16* ring_lo   = (u16*)((char*)outp + 768 + 65536);
  float* out2    = outp + 3 * 32 * 512;                 // final-layer fp32 output [B][S][H]

  const int tid  = threadIdx.x;
  const int w    = tid >> 6;
  const int lane = tid & 63;
  const int ln16 = lane & 15;
  const int kgrp = lane >> 4;
  const int jt   = w & 1;
  const int bt   = w >> 1;
  const int pid  = jg * 2 + jt;              // producer-wave id within (L, bt), [0,32)
  const int jc   = jg * 32 + jt * 16 + ln16; // output column
  const int bloc = bt * 16 + ln16;           // A-frag batch row

  // ---- preload step-invariant weights into VGPRs as hi/lo B-frags ----
  half8 Bhi[KT_ALL], Blo[KT_ALL];
#pragma unroll
  for (int kt = 0; kt < KT_ALL; ++kt) {
    const float* wp;
    if (L == 0) wp = (kt < 4) ? (w_ih0 + jc * 128 + kt * 32 + kgrp * 8)
                              : (w_hhs + jc * 512 + (kt - 4) * 32 + kgrp * 8);
    else        wp = (kt < 16) ? (w_ihs + (L - 1) * 512 * 512 + jc * 512 + kt * 32 + kgrp * 8)
                               : (w_hhs + L * 512 * 512 + jc * 512 + (kt - 16) * 32 + kgrp * 8);
    frag_from_f32(wp, Bhi[kt], Blo[kt]);
  }
  const float bias = b_ihs[L * 512 + jc] + b_hhs[L * 512 + jc];

  const u16* inPlaneHi = (L == 1) ? p0hi : p1hi;  // upstream plane (unused for L0)
  const u16* inPlaneLo = (L == 1) ? p0lo : p1lo;
  u16* myHi = (L == 0) ? p0hi : p1hi;             // own output plane (L<2)
  u16* myLo = (L == 0) ? p0lo : p1lo;

  const int sibBase = (L * 2 + bt) * 32;
  const int upBase  = (L > 0) ? ((L - 1) * 2 + bt) * 32 : 0;

  for (int t = 0; t < 1024; ++t) {
    // ---- gate: lanes 0-31 sibling flags >= t, lanes 32-63 upstream >= t+1 ----
    {
      bool need; const uint32* p; uint32 tgt;
      if (lane < 32) { need = (t > 0);  p = &flags[sibBase + lane];        tgt = (uint32)t; }
      else           { need = (L > 0);  p = &flags[upBase + (lane - 32)];  tgt = (uint32)(t + 1); }
      int spins = 0; bool ok = false;
      while (true) {
        bool pass = !need || (__hip_atomic_load(p, __ATOMIC_RELAXED, SCOPE_AGENT) >= tgt);
        if (__all(pass)) { ok = true; break; }
        if (++spins > 400000) break;           // ~100 ms cap: degrade, never hang
        if (spins > 64) __builtin_amdgcn_s_sleep(1);
      }
      if (!ok) return;
      (void)__hip_atomic_load(&flags[0], __ATOMIC_ACQUIRE, SCOPE_AGENT);  // invalidate caches
    }

    // ---- per-step source bases ----
    const u16*   iH = inPlaneHi + ((long)t * 32 + bloc) * 512;
    const u16*   iL = inPlaneLo + ((long)t * 32 + bloc) * 512;
    const float* xF = x + ((long)bloc * 1024 + t) * 128;
    const u16*rH, *rL;
    if (L < 2) { rH = myHi + ((long)(t - 1) * 32 + bloc) * 512;
                 rL = myLo + ((long)(t - 1) * 32 + bloc) * 512; }
    else       { int s = (t - 1) & 1;
                 rH = ring_hi + (s * 32 + bloc) * 512;
                 rL = ring_lo + (s * 32 + bloc) * 512; }
    const float* rF = h0 + (L * 32 + bloc) * 512;

    f32x4 C = {0.f, 0.f, 0.f, 0.f}, Xa = C, Xb = C;

    if (t == 0) {  // cold path: recurrent operand from h0 (fp32 split)
#pragma unroll
      for (int kt = 0; kt < KT_ALL; ++kt) {
        half8 Ahi, Alo;
        if (kt < KT_IN) {
          const int k = kt * 32 + kgrp * 8;
          if (L == 0) frag_from_f32(xF + k, Ahi, Alo);
          else { Ahi = *(const half8*)(iH + k); Alo = *(const half8*)(iL + k); }
        } else {
          const int k = (kt - KT_IN) * 32 + kgrp * 8;
          frag_from_f32(rF + k, Ahi, Alo);
        }
        C  = __builtin_amdgcn_mfma_f32_16x16x32_f16(Ahi, Bhi[kt], C, 0, 0, 0);
        Xa = __builtin_amdgcn_mfma_f32_16x16x32_f16(Ahi, Blo[kt], Xa, 0, 0, 0);
        Xb = __builtin_amdgcn_mfma_f32_16x16x32_f16(Alo, Bhi[kt], Xb, 0, 0, 0);
      }
    } else {       // hot path: all operands are direct f16 dwordx4 loads
#pragma unroll
      for (int kt = 0; kt < KT_ALL; ++kt) {
        half8 Ahi, Alo;
        if (kt < KT_IN) {
          const int k = kt * 32 + kgrp * 8;
          if (L == 0) frag_from_f32(xF + k, Ahi, Alo);
          else { Ahi = *(const half8*)(iH + k); Alo = *(const half8*)(iL + k); }
        } else {
          const int k = (kt - KT_IN) * 32 + kgrp * 8;
          Ahi = *(const half8*)(rH + k); Alo = *(const half8*)(rL + k);
        }
        C  = __builtin_amdgcn_mfma_f32_16x16x32_f16(Ahi, Bhi[kt], C, 0, 0, 0);
        Xa = __builtin_amdgcn_mfma_f32_16x16x32_f16(Ahi, Blo[kt], Xa, 0, 0, 0);
        Xb = __builtin_amdgcn_mfma_f32_16x16x32_f16(Alo, Bhi[kt], Xb, 0, 0, 0);
      }
    }

    // ---- epilogue: this wave owns its 16x16 tile outright ----
    f32x4 P = C + (Xa + Xb) * (1.0f / 4096.0f);
    const int b0 = bt * 16 + kgrp * 4;  // C/D: col=lane&15, row=(lane>>4)*4+r
#pragma unroll
    for (int r = 0; r < 4; ++r) {
      const float yv = fast_tanh(P[r] + bias);
      const int b = b0 + r;
      _Float16 hi = (_Float16)yv;
      _Float16 lo = (_Float16)((yv - (float)hi) * 4096.0f);
      if (L < 2) {
        myHi[((long)t * 32 + b) * 512 + jc] = *(u16*)&hi;
        myLo[((long)t * 32 + b) * 512 + jc] = *(u16*)&lo;
      } else {
        out2[((long)b * 1024 + t) * 512 + jc] = yv;
        const int s = t & 1;
        ring_hi[(s * 32 + b) * 512 + jc] = *(u16*)&hi;
        ring_lo[(s * 32 + b) * 512 + jc] = *(u16*)&lo;
      }
    }
    if (lane == 0)
      __hip_atomic_store(&flags[sibBase + pid], (uint32)(t + 1), __ATOMIC_RELEASE, SCOPE_AGENT);
  }
}

__global__ __launch_bounds__(256, 1) void rnn_persist(
    const float* __restrict__ x, const float* __restrict__ h0,
    const float* __restrict__ w_ih0, const float* __restrict__ w_ihs,
    const float* __restrict__ w_hhs, const float* __restrict__ b_ihs,
    const float* __restrict__ b_hhs,
    u16* __restrict__ p0hi, u16* __restrict__ p0lo,
    u16* __restrict__ p1hi, u16* __restrict__ p1lo,
    float* __restrict__ outp) {
  const int bid = blockIdx.x;
  const int l  = bid >> 4;
  const int jg = bid & 15;
  if (l == 0)      run_layer<0>(x, h0, w_ih0, w_ihs, w_hhs, b_ihs, b_hhs, p0hi, p0lo, p1hi, p1lo, outp, jg);
  else if (l == 1) run_layer<1>(x, h0, w_ih0, w_ihs, w_hhs, b_ihs, b_hhs, p0hi, p0lo, p1hi, p1lo, outp, jg);
  else             run_layer<2>(x, h0, w_ih0, w_ihs, w_hhs, b_ihs, b_hhs, p0hi, p0lo, p1hi, p1lo, outp, jg);
}

// hidden[l][b][j]: l<2 from plane slot 1023, l==2 from out2[:,1023,:].
// Runs after rnn_persist -> safely overwrites the flag/ring scratch.
__global__ __launch_bounds__(256) void finals_kernel(
    const u16* __restrict__ p0hi, const u16* __restrict__ p0lo,
    const u16* __restrict__ p1hi, const u16* __restrict__ p1lo,
    float* __restrict__ outp) {
  int i = blockIdx.x * 256 + threadIdx.x;
  if (i >= 3 * 32 * 512) return;
  int l = i >> 14;
  int r = i & 16383;
  int b = r >> 9, j = r & 511;
  float v;
  if (l == 2) {
    v = outp[3 * 32 * 512 + ((long)b * 1024 + 1023) * 512 + j];
  } else {
    const u16* hi = l ? p1hi : p0hi;
    const u16* lo = l ? p1lo : p0lo;
    u16 uh = hi[((long)1023 * 32 + b) * 512 + j];
    u16 ul = lo[((long)1023 * 32 + b) * 512 + j];
    _Float16 fh = *(_Float16*)&uh, fl = *(_Float16*)&ul;
    v = (float)fh + (float)fl * (1.0f / 4096.0f);
  }
  outp[i] = v;
}

extern "C" void kernel_launch(void* const* d_in, const int* in_sizes, int n_in,
                              void* d_out, int out_size, void* d_ws, size_t ws_size,
                              hipStream_t stream) {
  const float* x     = (const float*)d_in[0];
  const float* h0    = (const float*)d_in[1];
  const float* w_ih0 = (const float*)d_in[2];
  const float* w_ihs = (const float*)d_in[3];
  const float* w_hhs = (const float*)d_in[4];
  const float* b_ihs = (const float*)d_in[5];
  const float* b_hhs = (const float*)d_in[6];

  u16* p0hi = (u16*)d_ws;                  // 4 x 32 MiB separated hi/lo activation planes
  u16* p0lo = p0hi + PLANE_HALF_ELEMS;
  u16* p1hi = p0lo + PLANE_HALF_ELEMS;
  u16* p1lo = p1hi + PLANE_HALF_ELEMS;

  hipMemsetAsync(d_out, 0, 768, stream);   // zero the 192 flag counters
  rnn_persist<<<48, 256, 0, stream>>>(x, h0, w_ih0, w_ihs, w_hhs, b_ihs, b_hhs,
                                      p0hi, p0lo, p1hi, p1lo, (float*)d_out);
  finals_kernel<<<(3 * 32 * 512 + 255) / 256, 256, 0, stream>>>(p0hi, p0lo, p1hi, p1lo,
                                                                (float*)d_out);
}

// Round 4
// 11520.655 us; speedup vs baseline: 1.8077x; 1.8077x over previous
//
#include <hip/hip_runtime.h>

// Persistent barrier-free pipelined 3-layer tanh RNN, B=32, S=1024, I=128, H=512.
// 96 blocks = 6 stages x 16 jg. Stages: L0/L1/L2 recurrent (K=512, Whh in 128
// VGPRs), H0/H1/H2 input-projection helpers (decoupled, 64-step ring slack).
// All cross-block data in 64-deep MALL-resident rings accessed ONLY via
// relaxed agent atomics (sc1, NO buffer_inv/wbl2 cache maintenance). Ordering:
// explicit s_waitcnt vmcnt(0) before each flag publish. f16 split-2 precision
// (hi + lo*2^-12, 3 MFMA products). No __syncthreads, no LDS.

typedef _Float16 half8 __attribute__((ext_vector_type(8)));
typedef float f32x4 __attribute__((ext_vector_type(4)));
typedef unsigned int uint32;
typedef unsigned long long u64;
typedef unsigned short u16;

#define SCOPE_AGENT __HIP_MEMORY_SCOPE_AGENT
#define RING_D 64
#define RING_ELEMS (RING_D * 32 * 512)   // dwords per ring (4 MiB); 6 rings = 24 MiB
#define HID (3 * 32 * 512)
#define NFLAGS (6 * 2 * 32)

__device__ __forceinline__ uint32 aload(const uint32* p) {
  return __hip_atomic_load(p, __ATOMIC_RELAXED, SCOPE_AGENT);
}
__device__ __forceinline__ u64 aload64(const uint32* p) {
  return __hip_atomic_load((const u64*)p, __ATOMIC_RELAXED, SCOPE_AGENT);
}
__device__ __forceinline__ void astore(uint32* p, uint32 v) {
  __hip_atomic_store(p, v, __ATOMIC_RELAXED, SCOPE_AGENT);
}

struct HL { half8 hi, lo; };

__device__ __forceinline__ HL split_frag(const float* p) {
  float v[8];
  *(float4*)(v)     = *(const float4*)(p);
  *(float4*)(v + 4) = *(const float4*)(p + 4);
  union { _Float16 e[8]; half8 h; } H, Lo;
#pragma unroll
  for (int i = 0; i < 8; ++i) {
    _Float16 h = (_Float16)v[i];
    H.e[i] = h;
    Lo.e[i] = (_Float16)((v[i] - (float)h) * 4096.0f);  // exact residual, scaled to f16 normal range
  }
  HL r; r.hi = H.h; r.lo = Lo.h; return r;
}

// pair dword: low16 = hi-f16 bits, high16 = lo-f16 bits
__device__ __forceinline__ HL load_pair_frag(const uint32* p) {
  u64 q0 = aload64(p), q1 = aload64(p + 2), q2 = aload64(p + 4), q3 = aload64(p + 6);
  uint32 d0 = (uint32)q0, d1 = (uint32)(q0 >> 32), d2 = (uint32)q1, d3 = (uint32)(q1 >> 32);
  uint32 d4 = (uint32)q2, d5 = (uint32)(q2 >> 32), d6 = (uint32)q3, d7 = (uint32)(q3 >> 32);
  union { uint32 u[4]; half8 h; } H, Lo;
  H.u[0] = (d0 & 0xFFFFu) | (d1 << 16);  H.u[1] = (d2 & 0xFFFFu) | (d3 << 16);
  H.u[2] = (d4 & 0xFFFFu) | (d5 << 16);  H.u[3] = (d6 & 0xFFFFu) | (d7 << 16);
  Lo.u[0] = (d0 >> 16) | (d1 & 0xFFFF0000u);  Lo.u[1] = (d2 >> 16) | (d3 & 0xFFFF0000u);
  Lo.u[2] = (d4 >> 16) | (d5 & 0xFFFF0000u);  Lo.u[3] = (d6 >> 16) | (d7 & 0xFFFF0000u);
  HL r; r.hi = H.h; r.lo = Lo.h; return r;
}

__device__ __forceinline__ uint32 pack_pair(float x) {
  _Float16 h = (_Float16)x;
  _Float16 l = (_Float16)((x - (float)h) * 4096.0f);
  union { _Float16 f; u16 u; } ch, cl; ch.f = h; cl.f = l;
  return (uint32)ch.u | ((uint32)cl.u << 16);
}

__device__ __forceinline__ float fast_tanh(float x) {
  x = fminf(20.0f, fmaxf(-20.0f, x));
  float t = __builtin_amdgcn_exp2f(x * 2.885390081777927f);  // e^{2x}
  return (t - 1.0f) * __builtin_amdgcn_rcpf(t + 1.0f);
}

// wave-wide gate: per-lane up to two (flag >= target) conditions, __all-combined.
__device__ __forceinline__ bool gate2(const uint32* pa, uint32 ta, bool na,
                                      const uint32* pb, uint32 tb, bool nb) {
  int spins = 0;
  while (true) {
    bool pass = (!na || aload(pa) >= ta) && (!nb || aload(pb) >= tb);
    if (__all(pass)) break;
    if (++spins > 150000) return false;        // ~tens of ms cap: degrade, never hang
    if (spins > 16) __builtin_amdgcn_s_sleep(1);
  }
  asm volatile("" ::: "memory");               // no buffer_inv: all shared reads are sc1
  return true;
}

#define MFMA16(A, B, C) __builtin_amdgcn_mfma_f32_16x16x32_f16(A, B, C, 0, 0, 0)

// ---- recurrent stage X: h_t = tanh(p_X[t] + Whh_X . h_{t-1} + bias) ----
template <int X>
__device__ void run_rec(const float* __restrict__ h0, const float* __restrict__ w_hhs,
                        const float* __restrict__ b_ihs, const float* __restrict__ b_hhs,
                        uint32* __restrict__ ws, float* __restrict__ outp, int jg) {
  uint32* flags = (uint32*)outp;
  float* out2 = outp + HID;
  uint32* hr = ws + X * RING_ELEMS;         // own h ring (pair dwords)
  uint32* pr = ws + (3 + X) * RING_ELEMS;   // own p ring (fp32 dwords)

  const int tid = threadIdx.x, w = tid >> 6, lane = tid & 63;
  const int ln16 = lane & 15, kgrp = lane >> 4;
  const int jt = w & 1, bt = w >> 1;
  const int wid = jg * 2 + jt;
  const int jc = jg * 32 + jt * 16 + ln16;
  const int bloc = bt * 16 + ln16;
  const int l32 = lane & 31;
  const int b0 = bt * 16 + kgrp * 4;

  HL Wf[16];
#pragma unroll
  for (int kt = 0; kt < 16; ++kt)
    Wf[kt] = split_frag(w_hhs + (long)X * 512 * 512 + (long)jc * 512 + kt * 32 + kgrp * 8);
  const float bias = b_ihs[X * 512 + jc] + b_hhs[X * 512 + jc];

  // gate ptrs: lane<32 -> sibling L_X flags; lane>=32 -> helper H_X flags (+ ring guard H_{X+1})
  const uint32* pa = (lane < 32) ? &flags[(X * 2 + bt) * 32 + l32]
                                 : &flags[((3 + X) * 2 + bt) * 32 + l32];
  const uint32* pb = (X < 2) ? &flags[((4 + X) * 2 + bt) * 32 + l32] : pa;
  uint32* myflag = &flags[(X * 2 + bt) * 32 + wid];

  for (int t = 0; t < 1024; ++t) {
    const uint32 ta = (lane < 32) ? (uint32)t : (uint32)(t + 1);
    const bool   na = (lane < 32) ? (t > 0) : true;
    const bool   nb = (lane >= 32) && (X < 2) && (t >= 64);
    if (!gate2(pa, ta, na, pb, (uint32)(t - 63), nb)) return;

    f32x4 C = {0.f, 0.f, 0.f, 0.f}, Xa = C, Xb = C;
    if (t == 0) {
      const float* rF = h0 + ((long)X * 32 + bloc) * 512;
#pragma unroll
      for (int kt = 0; kt < 16; ++kt) {
        HL A = split_frag(rF + kt * 32 + kgrp * 8);
        C  = MFMA16(A.hi, Wf[kt].hi, C);
        Xa = MFMA16(A.hi, Wf[kt].lo, Xa);
        Xb = MFMA16(A.lo, Wf[kt].hi, Xb);
      }
    } else {
      const uint32* rbase = hr + ((long)((t - 1) & 63) * 32 + bloc) * 512;
#pragma unroll
      for (int kt = 0; kt < 16; ++kt) {
        HL A = load_pair_frag(rbase + kt * 32 + kgrp * 8);
        C  = MFMA16(A.hi, Wf[kt].hi, C);
        Xa = MFMA16(A.hi, Wf[kt].lo, Xa);
        Xb = MFMA16(A.lo, Wf[kt].hi, Xb);
      }
    }

    const uint32* pbase = pr + ((long)(t & 63) * 32) * 512;
    float pv[4];
#pragma unroll
    for (int r = 0; r < 4; ++r) pv[r] = __uint_as_float(aload(pbase + (b0 + r) * 512 + jc));

    f32x4 P = C + (Xa + Xb) * (1.0f / 4096.0f);
    uint32* hb = hr + ((long)(t & 63) * 32) * 512;
#pragma unroll
    for (int r = 0; r < 4; ++r) {
      float y = fast_tanh(P[r] + pv[r] + bias);
      astore(hb + (b0 + r) * 512 + jc, pack_pair(y));
      if (X == 2) out2[((long)(b0 + r) * 1024 + t) * 512 + jc] = y;
    }
    asm volatile("s_waitcnt vmcnt(0)" ::: "memory");  // drain sc1 stores before publish
    astore(myflag, (uint32)(t + 1));
  }
}

// ---- helper stage X: p_X[t] = Wih_X . in_X[t] (in_0 = x, in_{1,2} = h ring of L_{X-1}) ----
template <int X>
__device__ void run_help(const float* __restrict__ x, const float* __restrict__ w_ih0,
                         const float* __restrict__ w_ihs,
                         uint32* __restrict__ ws, float* __restrict__ outp, int jg) {
  uint32* flags = (uint32*)outp;
  uint32* pr = ws + (3 + X) * RING_ELEMS;
  const uint32* srcr = ws + (X > 0 ? (X - 1) : 0) * RING_ELEMS;

  const int tid = threadIdx.x, w = tid >> 6, lane = tid & 63;
  const int ln16 = lane & 15, kgrp = lane >> 4;
  const int jt = w & 1, bt = w >> 1;
  const int wid = jg * 2 + jt;
  const int jc = jg * 32 + jt * 16 + ln16;
  const int bloc = bt * 16 + ln16;
  const int l32 = lane & 31;
  const int b0 = bt * 16 + kgrp * 4;

  constexpr int NKT = (X == 0) ? 4 : 16;
  HL Wf[NKT];
#pragma unroll
  for (int kt = 0; kt < NKT; ++kt) {
    const float* wp;
    if constexpr (X == 0) wp = w_ih0 + (long)jc * 128 + kt * 32 + kgrp * 8;
    else                  wp = w_ihs + (long)(X - 1) * 512 * 512 + (long)jc * 512 + kt * 32 + kgrp * 8;
    Wf[kt] = split_frag(wp);
  }

  // gate: lane<32 -> upstream L_{X-1} >= t+1 (X>0 only); lane>=32 -> ring guard L_X >= t-63
  const uint32* pa = (lane < 32) ? &flags[((X > 0 ? X - 1 : 0) * 2 + bt) * 32 + l32]
                                 : &flags[(X * 2 + bt) * 32 + l32];
  uint32* myflag = &flags[((3 + X) * 2 + bt) * 32 + wid];

  for (int t = 0; t < 1024; ++t) {
    const uint32 ta = (lane < 32) ? (uint32)(t + 1) : (uint32)(t - 63);
    const bool   na = (lane < 32) ? (X > 0) : (t >= 64);
    if (!gate2(pa, ta, na, pa, 0, false)) return;

    f32x4 C = {0.f, 0.f, 0.f, 0.f}, Xa = C, Xb = C;
    if constexpr (X == 0) {
      const float* xF = x + ((long)bloc * 1024 + t) * 128;
#pragma unroll
      for (int kt = 0; kt < 4; ++kt) {
        HL A = split_frag(xF + kt * 32 + kgrp * 8);
        C  = MFMA16(A.hi, Wf[kt].hi, C);
        Xa = MFMA16(A.hi, Wf[kt].lo, Xa);
        Xb = MFMA16(A.lo, Wf[kt].hi, Xb);
      }
    } else {
      const uint32* ibase = srcr + ((long)(t & 63) * 32 + bloc) * 512;
#pragma unroll
      for (int kt = 0; kt < 16; ++kt) {
        HL A = load_pair_frag(ibase + kt * 32 + kgrp * 8);
        C  = MFMA16(A.hi, Wf[kt].hi, C);
        Xa = MFMA16(A.hi, Wf[kt].lo, Xa);
        Xb = MFMA16(A.lo, Wf[kt].hi, Xb);
      }
    }

    f32x4 P = C + (Xa + Xb) * (1.0f / 4096.0f);
    uint32* pb2 = pr + ((long)(t & 63) * 32) * 512;
#pragma unroll
    for (int r = 0; r < 4; ++r)
      astore(pb2 + (b0 + r) * 512 + jc, __float_as_uint(P[r]));
    asm volatile("s_waitcnt vmcnt(0)" ::: "memory");
    astore(myflag, (uint32)(t + 1));
  }
}

__global__ __launch_bounds__(256, 1) void rnn_persist(
    const float* __restrict__ x, const float* __restrict__ h0,
    const float* __restrict__ w_ih0, const float* __restrict__ w_ihs,
    const float* __restrict__ w_hhs, const float* __restrict__ b_ihs,
    const float* __restrict__ b_hhs, uint32* __restrict__ ws,
    float* __restrict__ outp) {
  const int bid = blockIdx.x;
  const int g = bid >> 4, jg = bid & 15;
  switch (g) {
    case 0: run_rec<0>(h0, w_hhs, b_ihs, b_hhs, ws, outp, jg); break;
    case 1: run_rec<1>(h0, w_hhs, b_ihs, b_hhs, ws, outp, jg); break;
    case 2: run_rec<2>(h0, w_hhs, b_ihs, b_hhs, ws, outp, jg); break;
    case 3: run_help<0>(x, w_ih0, w_ihs, ws, outp, jg); break;
    case 4: run_help<1>(x, w_ih0, w_ihs, ws, outp, jg); break;
    case 5: run_help<2>(x, w_ih0, w_ihs, ws, outp, jg); break;
  }
}

// hidden[l][b][j]: l<2 from h-ring slot 63 (t=1023), l==2 from out2[:,1023,:].
__global__ __launch_bounds__(256) void finals_kernel(const uint32* __restrict__ ws,
                                                     float* __restrict__ outp) {
  int i = blockIdx.x * 256 + threadIdx.x;
  if (i >= HID) return;
  int l = i >> 14, r = i & 16383, b = r >> 9, j = r & 511;
  float v;
  if (l == 2) {
    v = outp[HID + ((long)b * 1024 + 1023) * 512 + j];
  } else {
    uint32 p = ws[(long)l * RING_ELEMS + ((63 * 32 + b) * 512 + j)];
    u16 uh = (u16)(p & 0xFFFFu), ul = (u16)(p >> 16);
    _Float16 fh = *(_Float16*)&uh, fl = *(_Float16*)&ul;
    v = (float)fh + (float)fl * (1.0f / 4096.0f);
  }
  outp[i] = v;
}

extern "C" void kernel_launch(void* const* d_in, const int* in_sizes, int n_in,
                              void* d_out, int out_size, void* d_ws, size_t ws_size,
                              hipStream_t stream) {
  const float* x     = (const float*)d_in[0];
  const float* h0    = (const float*)d_in[1];
  const float* w_ih0 = (const float*)d_in[2];
  const float* w_ihs = (const float*)d_in[3];
  const float* w_hhs = (const float*)d_in[4];
  const float* b_ihs = (const float*)d_in[5];
  const float* b_hhs = (const float*)d_in[6];

  hipMemsetAsync(d_out, 0, NFLAGS * sizeof(uint32), stream);  // zero flag counters
  rnn_persist<<<96, 256, 0, stream>>>(x, h0, w_ih0, w_ihs, w_hhs, b_ihs, b_hhs,
                                      (uint32*)d_ws, (float*)d_out);
  finals_kernel<<<(HID + 255) / 256, 256, 0, stream>>>((const uint32*)d_ws, (float*)d_out);
}